// Round 19
// baseline (566.029 us; speedup 1.0000x reference)
//
#include <hip/hip_runtime.h>
#include <hip/hip_bf16.h>

#define N_TAG 128
#define T_LEN 512
#define START_TAG 126
#define STOP_TAG 127

typedef __attribute__((ext_vector_type(8))) __bf16 bf16x8;
typedef __attribute__((ext_vector_type(4))) float f32x4;

// Round 19 = r10 (149us, absmax 0) with the DP loop's DS traffic eliminated.
// Theory: LDS pipe is per-CU; r10's 32 ds_bpermute/step x ~4-5 waves/CU
// serialize ~500-700cy/step (r17: 2x waves/CU -> +870cy/step confirms).
// Fix: each lane loads its 32 EF values straight from global in C-frag
// order (tau quads are contiguous: 8x dwordx4/step), double-buffered P/Q
// with one-full-iteration prefetch distance; exp applied in-lane on the
// per-SIMD trans pipe. Zero DS ops in the DP loop. All else r10 verbatim.
__global__ __launch_bounds__(320, 1)
void crf_split_kernel(const float* __restrict__ feats,
                      const float* __restrict__ trans,
                      const int* __restrict__ tags,
                      float* __restrict__ out) {
  const int tid = threadIdx.x;
  const int wid = tid >> 6;
  const int lane = tid & 63;
  const int bbase = blockIdx.x * 2;

  __shared__ float Uf[2][N_TAG];
  __shared__ float Wb[2][N_TAG];
  __shared__ float LZ[4];
  __shared__ float GOLD[2];

  if (wid == 4) {
    // ---- gold wave: lanes 0-31 batch 0, lanes 32-63 batch 1 ----
    const int half = lane >> 5, tl = lane & 31;
    const int b = bbase + half;
    const int* tg = tags + (size_t)b * T_LEN;
    const float* fg = feats + (size_t)b * T_LEN * N_TAG;
    float gsum = 0.f;
    for (int t = tl; t < T_LEN; t += 32) {
      int tag = tg[t];
      int prev = (t == 0) ? START_TAG : tg[t - 1];
      gsum += trans[(size_t)tag * N_TAG + prev] + fg[(size_t)t * N_TAG + tag];
      if (t == T_LEN - 1) gsum += trans[STOP_TAG * N_TAG + tag];
    }
#pragma unroll
    for (int s = 16; s; s >>= 1) gsum += __shfl_xor(gsum, s);
    if (tl == 0) GOLD[half] = gsum;
    __syncthreads();
#pragma unroll
    for (int bL = 0; bL < 2; ++bL) {
      float sd = Uf[bL][lane] * Wb[bL][lane] +
                 Uf[bL][lane + 64] * Wb[bL][lane + 64];
#pragma unroll
      for (int s = 32; s; s >>= 1) sd += __shfl_xor(sd, s);
      if (lane == 0)
        out[bbase + bL] = __logf(sd) + LZ[2 * bL] + LZ[2 * bL + 1] - GOLD[bL];
    }
    return;
  }

  // ---- main DP waves: wid = 2*bL + dir (dir 0 fwd, 1 bwd) ----
  const int bL = wid >> 1, dir = wid & 1;
  const int batch = bbase + bL;
  const int n = lane & 15, g = lane >> 4;
  const float* fbase = feats + (size_t)batch * T_LEN * N_TAG;
  const int T0 = dir ? 510 : 0;
  const int TS = dir ? -1 : 1;

  // ---- A fragments: tile mt holds E rows tau(mt, ridx); lane supplies
  //      row ridx=n, elements k = 32kk+8g+j. fwd: E[tau][k]; bwd: E[k][tau].
  bf16x8 A[8][4];
#pragma unroll
  for (int mt = 0; mt < 8; ++mt) {
    const int tau = 32 * (mt >> 1) + 8 * (n >> 2) + 4 * (mt & 1) + (n & 3);
#pragma unroll
    for (int kk = 0; kk < 4; ++kk) {
      bf16x8 v;
      if (dir == 0) {
        const float* p = trans + (size_t)tau * N_TAG + 32 * kk + 8 * g;
        f32x4 x = *(const f32x4*)p;
        f32x4 y = *(const f32x4*)(p + 4);
        v[0] = (__bf16)__expf(x[0]); v[1] = (__bf16)__expf(x[1]);
        v[2] = (__bf16)__expf(x[2]); v[3] = (__bf16)__expf(x[3]);
        v[4] = (__bf16)__expf(y[0]); v[5] = (__bf16)__expf(y[1]);
        v[6] = (__bf16)__expf(y[2]); v[7] = (__bf16)__expf(y[3]);
      } else {
#pragma unroll
        for (int j = 0; j < 8; ++j)
          v[j] = (__bf16)__expf(trans[(size_t)(32 * kk + 8 * g + j) * N_TAG + tau]);
      }
      A[mt][kk] = v;
    }
  }

  // ---- B init ----
  bf16x8 Bv[4];
#pragma unroll
  for (int kk = 0; kk < 4; ++kk) {
    bf16x8 z;
#pragma unroll
    for (int j = 0; j < 8; ++j) z[j] = (__bf16)0.0f;
    Bv[kk] = z;
  }
  if (dir == 0) {
    if (g == 3) Bv[3][6] = (__bf16)1.0f;  // one-hot START=126: kk=3,g=3,j=6
  } else {
    const float* s127 = trans + (size_t)STOP_TAG * N_TAG;
    const float* f511 = fbase + (size_t)(T_LEN - 1) * N_TAG;
#pragma unroll
    for (int kk = 0; kk < 4; ++kk) {
      const int off = 32 * kk + 8 * g;
      f32x4 s0 = *(const f32x4*)(s127 + off);
      f32x4 s1 = *(const f32x4*)(s127 + off + 4);
      f32x4 e0 = *(const f32x4*)(f511 + off);
      f32x4 e1 = *(const f32x4*)(f511 + off + 4);
      bf16x8 v;
      v[0] = (__bf16)__expf(s0[0] + e0[0]); v[1] = (__bf16)__expf(s0[1] + e0[1]);
      v[2] = (__bf16)__expf(s0[2] + e0[2]); v[3] = (__bf16)__expf(s0[3] + e0[3]);
      v[4] = (__bf16)__expf(s1[0] + e1[0]); v[5] = (__bf16)__expf(s1[1] + e1[1]);
      v[6] = (__bf16)__expf(s1[2] + e1[2]); v[7] = (__bf16)__expf(s1[3] + e1[3]);
      Bv[kk] = v;
    }
  }

  const f32x4 FZ = {0.f, 0.f, 0.f, 0.f};
  float logZ = 0.0f;

  // EF buffer: EB[2a+bb] = feats[t][32a+8g+4bb .. +3]  (C-frag order, tau
  // quads contiguous). 8x dwordx4 per step, double-buffered P/Q.
  const float* fg8 = fbase + 8 * g;

#define LOADEF(BUF, K)                                                       \
  {                                                                          \
    const float* rp_ = fg8 + (size_t)(T0 + TS * (K)) * N_TAG;                \
    _Pragma("unroll") for (int a_ = 0; a_ < 4; ++a_)                         \
        _Pragma("unroll") for (int bb_ = 0; bb_ < 2; ++bb_)                  \
            BUF[2 * a_ + bb_] = *(const f32x4*)(rp_ + 32 * a_ + 4 * bb_);    \
  }

#define EXPB(BUF)                                                            \
  {                                                                          \
    _Pragma("unroll") for (int m_ = 0; m_ < 8; ++m_) {                       \
      BUF[m_][0] = __expf(BUF[m_][0]); BUF[m_][1] = __expf(BUF[m_][1]);      \
      BUF[m_][2] = __expf(BUF[m_][2]); BUF[m_][3] = __expf(BUF[m_][3]);      \
    }                                                                        \
  }

#define RENORM(ACC)                                                          \
  {                                                                          \
    float mx_ = ACC[0][0];                                                   \
    _Pragma("unroll") for (int mt = 0; mt < 8; ++mt)                         \
        mx_ = fmaxf(mx_, fmaxf(fmaxf(ACC[mt][0], ACC[mt][1]),                \
                               fmaxf(ACC[mt][2], ACC[mt][3])));              \
    mx_ = fmaxf(mx_, __shfl_xor(mx_, 16));                                   \
    mx_ = fmaxf(mx_, __shfl_xor(mx_, 32));                                   \
    int eb_ = __float_as_int(mx_) & 0x7f800000;                              \
    float inv_ = __int_as_float(0x7f000000 - eb_); /* exact 2^-a */          \
    logZ += (float)((eb_ >> 23) - 127) * 0.69314718056f;                     \
    _Pragma("unroll") for (int mt = 0; mt < 8; ++mt) {                       \
      ACC[mt][0] *= inv_; ACC[mt][1] *= inv_;                                \
      ACC[mt][2] *= inv_; ACC[mt][3] *= inv_;                                \
    }                                                                        \
  }

  // One DP step: consume (exp'd) BUF, then prefetch BUF <- step KP2.
#define ITER(BUF, KP2, DOREN, DOPF)                                          \
  {                                                                          \
    EXPB(BUF);                                                               \
    f32x4 acc[8];                                                            \
    _Pragma("unroll") for (int mt = 0; mt < 8; ++mt)                         \
        acc[mt] = __builtin_amdgcn_mfma_f32_16x16x32_bf16(                   \
            A[mt][0], Bv[0], FZ, 0, 0, 0);                                   \
    _Pragma("unroll") for (int kk = 1; kk < 4; ++kk) {                       \
      _Pragma("unroll") for (int mt = 0; mt < 8; ++mt)                       \
          acc[mt] = __builtin_amdgcn_mfma_f32_16x16x32_bf16(                 \
              A[mt][kk], Bv[kk], acc[mt], 0, 0, 0);                          \
    }                                                                        \
    _Pragma("unroll") for (int mt = 0; mt < 8; ++mt) {                       \
      acc[mt][0] *= BUF[mt][0]; acc[mt][1] *= BUF[mt][1];                    \
      acc[mt][2] *= BUF[mt][2]; acc[mt][3] *= BUF[mt][3];                    \
    }                                                                        \
    if (DOREN) RENORM(acc);                                                  \
    _Pragma("unroll") for (int kk = 0; kk < 4; ++kk) {                       \
      bf16x8 nb;                                                             \
      nb[0] = (__bf16)acc[2 * kk][0];     nb[1] = (__bf16)acc[2 * kk][1];    \
      nb[2] = (__bf16)acc[2 * kk][2];     nb[3] = (__bf16)acc[2 * kk][3];    \
      nb[4] = (__bf16)acc[2 * kk + 1][0]; nb[5] = (__bf16)acc[2 * kk + 1][1];\
      nb[6] = (__bf16)acc[2 * kk + 1][2]; nb[7] = (__bf16)acc[2 * kk + 1][3];\
      Bv[kk] = nb;                                                           \
    }                                                                        \
    if (DOPF) LOADEF(BUF, KP2);                                              \
  }

  f32x4 P[8], Q[8];
  LOADEF(P, 0);
  LOADEF(Q, 1);

  // ---- 255 full steps + tail = 256 MFMA steps; renorm at k%4==3 ----
  for (int kb = 0; kb < 63; ++kb) {
    const int k0 = 4 * kb;
    ITER(P, k0 + 2, false, true);
    ITER(Q, k0 + 3, false, true);
    ITER(P, k0 + 4, false, true);
    ITER(Q, k0 + 5, true, true);
  }
  ITER(P, 254, false, true);   // k=252, prefetch P<-254
  ITER(Q, 255, false, true);   // k=253, prefetch Q<-255
  ITER(P, 0, false, false);    // k=254, no prefetch

  // ---- tail (k=255): fwd multiplies ef_255; bwd keeps raw E^T·b ----
  f32x4 upF[8];
  {
    EXPB(Q);
    f32x4 acc[8];
#pragma unroll
    for (int mt = 0; mt < 8; ++mt)
      acc[mt] = __builtin_amdgcn_mfma_f32_16x16x32_bf16(A[mt][0], Bv[0], FZ,
                                                        0, 0, 0);
#pragma unroll
    for (int kk = 1; kk < 4; ++kk) {
#pragma unroll
      for (int mt = 0; mt < 8; ++mt)
        acc[mt] = __builtin_amdgcn_mfma_f32_16x16x32_bf16(A[mt][kk], Bv[kk],
                                                          acc[mt], 0, 0, 0);
    }
    if (dir == 0) {
#pragma unroll
      for (int mt = 0; mt < 8; ++mt) {
        acc[mt][0] *= Q[mt][0]; acc[mt][1] *= Q[mt][1];
        acc[mt][2] *= Q[mt][2]; acc[mt][3] *= Q[mt][3];
      }
    }
    RENORM(acc);  // final normalization so the dot can't overflow f32
#pragma unroll
    for (int mt = 0; mt < 8; ++mt) upF[mt] = acc[mt];
  }

  // ---- publish final vectors (plain tag order) ----
  float* dst = (dir == 0) ? Uf[bL] : Wb[bL];
  if (n == 0) {
#pragma unroll
    for (int mt = 0; mt < 8; ++mt) {
      const int base = 32 * (mt >> 1) + 8 * g + 4 * (mt & 1);
#pragma unroll
      for (int r = 0; r < 4; ++r) dst[base + r] = upF[mt][r];
    }
  }
  if (lane == 0) LZ[wid] = logZ;
  __syncthreads();
#undef ITER
#undef RENORM
#undef EXPB
#undef LOADEF
}

extern "C" void kernel_launch(void* const* d_in, const int* in_sizes, int n_in,
                              void* d_out, int out_size, void* d_ws, size_t ws_size,
                              hipStream_t stream) {
  const float* feats = (const float*)d_in[0];
  const float* trans = (const float*)d_in[1];
  const int* tags = (const int*)d_in[2];
  float* out = (float*)d_out;
  int B = in_sizes[0] / (T_LEN * N_TAG);  // 512
  crf_split_kernel<<<B / 2, 320, 0, stream>>>(feats, trans, tags, out);
}

// Round 20
// 156.610 us; speedup vs baseline: 3.6143x; 3.6143x over previous
//
#include <hip/hip_runtime.h>
#include <hip/hip_bf16.h>

#define N_TAG 128
#define T_LEN 512
#define START_TAG 126
#define STOP_TAG 127

typedef __attribute__((ext_vector_type(8))) __bf16 bf16x8;
typedef __attribute__((ext_vector_type(4))) float f32x4;

// Round 20 = r10 (best measured: 149us, absmax 0, no spill) + two zero-risk
// edits: (1) kk=0 MFMA consumes constant-zero C (FZ) instead of 32 v_mov
// zero-inits per step; (2) s_setprio(1) around the MFMA cluster (free-running
// waves = the regime where setprio measured +4-7%). No new live registers.
__global__ __launch_bounds__(320, 1)
void crf_split_kernel(const float* __restrict__ feats,
                      const float* __restrict__ trans,
                      const int* __restrict__ tags,
                      float* __restrict__ out) {
  const int tid = threadIdx.x;
  const int wid = tid >> 6;
  const int lane = tid & 63;
  const int bbase = blockIdx.x * 2;

  __shared__ float Uf[2][N_TAG];
  __shared__ float Wb[2][N_TAG];
  __shared__ float LZ[4];
  __shared__ float GOLD[2];

  if (wid == 4) {
    // ---- gold wave: lanes 0-31 batch 0, lanes 32-63 batch 1 ----
    const int half = lane >> 5, tl = lane & 31;
    const int b = bbase + half;
    const int* tg = tags + (size_t)b * T_LEN;
    const float* fg = feats + (size_t)b * T_LEN * N_TAG;
    float gsum = 0.f;
    for (int t = tl; t < T_LEN; t += 32) {
      int tag = tg[t];
      int prev = (t == 0) ? START_TAG : tg[t - 1];
      gsum += trans[(size_t)tag * N_TAG + prev] + fg[(size_t)t * N_TAG + tag];
      if (t == T_LEN - 1) gsum += trans[STOP_TAG * N_TAG + tag];
    }
#pragma unroll
    for (int s = 16; s; s >>= 1) gsum += __shfl_xor(gsum, s);
    if (tl == 0) GOLD[half] = gsum;
    __syncthreads();
    // ---- combine ----
#pragma unroll
    for (int bL = 0; bL < 2; ++bL) {
      float sd = Uf[bL][lane] * Wb[bL][lane] +
                 Uf[bL][lane + 64] * Wb[bL][lane + 64];
#pragma unroll
      for (int s = 32; s; s >>= 1) sd += __shfl_xor(sd, s);
      if (lane == 0)
        out[bbase + bL] = __logf(sd) + LZ[2 * bL] + LZ[2 * bL + 1] - GOLD[bL];
    }
    return;
  }

  // ---- main DP waves: wid = 2*bL + dir (dir 0 fwd, 1 bwd) ----
  const int bL = wid >> 1, dir = wid & 1;
  const int batch = bbase + bL;
  const int n = lane & 15, g = lane >> 4;
  const float* fbase = feats + (size_t)batch * T_LEN * N_TAG;
  const int T0 = dir ? 510 : 0;
  const int TS = dir ? -1 : 1;
  const int ib = 32 * g;  // bpermute base byte address

  // ---- A fragments: tile mt holds E rows tau(mt, ridx); lane supplies
  //      row ridx=n, elements k = 32kk+8g+j. fwd: E[tau][k]; bwd: E[k][tau].
  bf16x8 A[8][4];
#pragma unroll
  for (int mt = 0; mt < 8; ++mt) {
    const int tau = 32 * (mt >> 1) + 8 * (n >> 2) + 4 * (mt & 1) + (n & 3);
#pragma unroll
    for (int kk = 0; kk < 4; ++kk) {
      bf16x8 v;
      if (dir == 0) {
        const float* p = trans + (size_t)tau * N_TAG + 32 * kk + 8 * g;
        f32x4 x = *(const f32x4*)p;
        f32x4 y = *(const f32x4*)(p + 4);
        v[0] = (__bf16)__expf(x[0]); v[1] = (__bf16)__expf(x[1]);
        v[2] = (__bf16)__expf(x[2]); v[3] = (__bf16)__expf(x[3]);
        v[4] = (__bf16)__expf(y[0]); v[5] = (__bf16)__expf(y[1]);
        v[6] = (__bf16)__expf(y[2]); v[7] = (__bf16)__expf(y[3]);
      } else {
#pragma unroll
        for (int j = 0; j < 8; ++j)
          v[j] = (__bf16)__expf(trans[(size_t)(32 * kk + 8 * g + j) * N_TAG + tau]);
      }
      A[mt][kk] = v;
    }
  }

  // ---- B init ----
  bf16x8 Bv[4];
#pragma unroll
  for (int kk = 0; kk < 4; ++kk) {
    bf16x8 z;
#pragma unroll
    for (int j = 0; j < 8; ++j) z[j] = (__bf16)0.0f;
    Bv[kk] = z;
  }
  if (dir == 0) {
    // u_{-1} = one-hot(START=126): tag 126 -> kk=3, g=3, j=6
    if (g == 3) Bv[3][6] = (__bf16)1.0f;
  } else {
    // b0 = ef_511 ⊙ s, s_j = exp(trans[STOP][j]); tag = 32kk+8g+j
    const float* s127 = trans + (size_t)STOP_TAG * N_TAG;
    const float* f511 = fbase + (size_t)(T_LEN - 1) * N_TAG;
#pragma unroll
    for (int kk = 0; kk < 4; ++kk) {
      const int off = 32 * kk + 8 * g;
      f32x4 s0 = *(const f32x4*)(s127 + off);
      f32x4 s1 = *(const f32x4*)(s127 + off + 4);
      f32x4 e0 = *(const f32x4*)(f511 + off);
      f32x4 e1 = *(const f32x4*)(f511 + off + 4);
      bf16x8 v;
      v[0] = (__bf16)__expf(s0[0] + e0[0]); v[1] = (__bf16)__expf(s0[1] + e0[1]);
      v[2] = (__bf16)__expf(s0[2] + e0[2]); v[3] = (__bf16)__expf(s0[3] + e0[3]);
      v[4] = (__bf16)__expf(s1[0] + e1[0]); v[5] = (__bf16)__expf(s1[1] + e1[1]);
      v[6] = (__bf16)__expf(s1[2] + e1[2]); v[7] = (__bf16)__expf(s1[3] + e1[3]);
      Bv[kk] = v;
    }
  }

  const f32x4 FZ = {0.f, 0.f, 0.f, 0.f};

  // ---- feat ring: slot s holds row t_cur (t==s mod 4); 2 dwords/lane ----
  float Lr[4][2];
#pragma unroll
  for (int s = 0; s < 4; ++s) {
    const float* rp = fbase + (size_t)(T0 + TS * s) * N_TAG;
    Lr[s][0] = rp[lane];
    Lr[s][1] = rp[lane + 64];
  }
  Lr[0][0] = __expf(Lr[0][0]);
  Lr[0][1] = __expf(Lr[0][1]);
  float logZ = 0.0f;

  // EF[mt][r] = ef[tau(mt,4g+r)]; tau = 32a+8g+4bb+r (a=mt>>1, bb=mt&1):
  // a<2 -> reg0 lane tau; a>=2 -> reg1 lane tau-64. Imm-offset bpermutes.
#define BPERM(DST, SLOT)                                                     \
  {                                                                          \
    _Pragma("unroll") for (int a = 0; a < 4; ++a) {                          \
      int sv_ = __float_as_int((a < 2) ? Lr[SLOT][0] : Lr[SLOT][1]);         \
      _Pragma("unroll") for (int bb = 0; bb < 2; ++bb) {                     \
        _Pragma("unroll") for (int r = 0; r < 4; ++r) {                      \
          int w_ = __builtin_amdgcn_ds_bpermute(                             \
              ib + 128 * (a & 1) + 16 * bb + 4 * r, sv_);                    \
          DST[2 * a + bb][r] = __int_as_float(w_);                           \
        }                                                                    \
      }                                                                      \
    }                                                                        \
  }

#define RENORM(ACC)                                                          \
  {                                                                          \
    float mx_ = ACC[0][0];                                                   \
    _Pragma("unroll") for (int mt = 0; mt < 8; ++mt)                         \
        mx_ = fmaxf(mx_, fmaxf(fmaxf(ACC[mt][0], ACC[mt][1]),                \
                               fmaxf(ACC[mt][2], ACC[mt][3])));              \
    mx_ = fmaxf(mx_, __shfl_xor(mx_, 16));                                   \
    mx_ = fmaxf(mx_, __shfl_xor(mx_, 32));                                   \
    int eb_ = __float_as_int(mx_) & 0x7f800000;                              \
    float inv_ = __int_as_float(0x7f000000 - eb_); /* exact 2^-a */          \
    logZ += (float)((eb_ >> 23) - 127) * 0.69314718056f;                     \
    _Pragma("unroll") for (int mt = 0; mt < 8; ++mt) {                       \
      ACC[mt][0] *= inv_; ACC[mt][1] *= inv_;                                \
      ACC[mt][2] *= inv_; ACC[mt][3] *= inv_;                                \
    }                                                                        \
  }

#define ITER(S, SX, KP4, DOREN)                                              \
  {                                                                          \
    f32x4 EF[8];                                                             \
    BPERM(EF, S);                                                            \
    f32x4 acc[8];                                                            \
    __builtin_amdgcn_s_setprio(1);                                           \
    _Pragma("unroll") for (int mt = 0; mt < 8; ++mt)                         \
        acc[mt] = __builtin_amdgcn_mfma_f32_16x16x32_bf16(                   \
            A[mt][0], Bv[0], FZ, 0, 0, 0);                                   \
    _Pragma("unroll") for (int kk = 1; kk < 4; ++kk) {                       \
      _Pragma("unroll") for (int mt = 0; mt < 8; ++mt)                       \
          acc[mt] = __builtin_amdgcn_mfma_f32_16x16x32_bf16(                 \
              A[mt][kk], Bv[kk], acc[mt], 0, 0, 0);                          \
    }                                                                        \
    __builtin_amdgcn_s_setprio(0);                                           \
    _Pragma("unroll") for (int mt = 0; mt < 8; ++mt) {                       \
      acc[mt][0] *= EF[mt][0]; acc[mt][1] *= EF[mt][1];                      \
      acc[mt][2] *= EF[mt][2]; acc[mt][3] *= EF[mt][3];                      \
    }                                                                        \
    if (DOREN) RENORM(acc);                                                  \
    _Pragma("unroll") for (int kk = 0; kk < 4; ++kk) {                       \
      bf16x8 nb;                                                             \
      nb[0] = (__bf16)acc[2 * kk][0];     nb[1] = (__bf16)acc[2 * kk][1];    \
      nb[2] = (__bf16)acc[2 * kk][2];     nb[3] = (__bf16)acc[2 * kk][3];    \
      nb[4] = (__bf16)acc[2 * kk + 1][0]; nb[5] = (__bf16)acc[2 * kk + 1][1];\
      nb[6] = (__bf16)acc[2 * kk + 1][2]; nb[7] = (__bf16)acc[2 * kk + 1][3];\
      Bv[kk] = nb;                                                           \
    }                                                                        \
    Lr[SX][0] = __expf(Lr[SX][0]); /* next step's ef (landed 3 iters ago) */ \
    Lr[SX][1] = __expf(Lr[SX][1]);                                           \
    {                                                                        \
      const float* rp_ = fbase + (size_t)(T0 + TS * (KP4)) * N_TAG;          \
      Lr[S][0] = rp_[lane]; /* refill slot: 4-iter lookahead */              \
      Lr[S][1] = rp_[lane + 64];                                             \
    }                                                                        \
  }

  // ---- 255 full steps + tail: 256 MFMA steps total ----
  for (int kb = 0; kb < 63; ++kb) {
    const int k0 = kb * 4;
    ITER(0, 1, k0 + 4, false);
    ITER(1, 2, k0 + 5, false);
    ITER(2, 3, k0 + 6, false);
    ITER(3, 0, k0 + 7, true);
  }
  ITER(0, 1, 256, false);  // k=252
  ITER(1, 2, 257, false);  // k=253
  ITER(2, 3, 258, false);  // k=254

  // ---- tail (k=255): fwd multiplies ef_255; bwd keeps raw E^T·b ----
  f32x4 upF[8];
  {
    f32x4 EF[8];
    BPERM(EF, 3);
    f32x4 acc[8];
    __builtin_amdgcn_s_setprio(1);
#pragma unroll
    for (int mt = 0; mt < 8; ++mt)
      acc[mt] = __builtin_amdgcn_mfma_f32_16x16x32_bf16(A[mt][0], Bv[0], FZ,
                                                        0, 0, 0);
#pragma unroll
    for (int kk = 1; kk < 4; ++kk) {
#pragma unroll
      for (int mt = 0; mt < 8; ++mt)
        acc[mt] = __builtin_amdgcn_mfma_f32_16x16x32_bf16(A[mt][kk], Bv[kk],
                                                          acc[mt], 0, 0, 0);
    }
    __builtin_amdgcn_s_setprio(0);
    if (dir == 0) {
#pragma unroll
      for (int mt = 0; mt < 8; ++mt) {
        acc[mt][0] *= EF[mt][0]; acc[mt][1] *= EF[mt][1];
        acc[mt][2] *= EF[mt][2]; acc[mt][3] *= EF[mt][3];
      }
    }
    RENORM(acc);  // final normalization so the dot can't overflow f32
#pragma unroll
    for (int mt = 0; mt < 8; ++mt) upF[mt] = acc[mt];
  }

  // ---- publish final vectors (plain tag order) ----
  float* dst = (dir == 0) ? Uf[bL] : Wb[bL];
  if (n == 0) {
#pragma unroll
    for (int mt = 0; mt < 8; ++mt) {
      const int base = 32 * (mt >> 1) + 8 * g + 4 * (mt & 1);
#pragma unroll
      for (int r = 0; r < 4; ++r) dst[base + r] = upF[mt][r];
    }
  }
  if (lane == 0) LZ[wid] = logZ;
  __syncthreads();
#undef ITER
#undef RENORM
#undef BPERM
}

extern "C" void kernel_launch(void* const* d_in, const int* in_sizes, int n_in,
                              void* d_out, int out_size, void* d_ws, size_t ws_size,
                              hipStream_t stream) {
  const float* feats = (const float*)d_in[0];
  const float* trans = (const float*)d_in[1];
  const int* tags = (const int*)d_in[2];
  float* out = (float*)d_out;
  int B = in_sizes[0] / (T_LEN * N_TAG);  // 512
  crf_split_kernel<<<B / 2, 320, 0, stream>>>(feats, trans, tags, out);
}

// Round 21
// 148.804 us; speedup vs baseline: 3.8039x; 1.0525x over previous
//
#include <hip/hip_runtime.h>
#include <hip/hip_bf16.h>

#define N_TAG 128
#define T_LEN 512
#define START_TAG 126
#define STOP_TAG 127

typedef __attribute__((ext_vector_type(8))) __bf16 bf16x8;
typedef __attribute__((ext_vector_type(4))) float f32x4;

// FINAL: exact round-10 kernel — best measured (149us harness, absmax 0,
// zero spill, zero bank conflicts). Split-direction exp-space CRF DP with
// zero-communication MFMA steps:
// score = log(s^T ∏ D_t E u0): forward wave computes u_255 (256 steps from
// one-hot START), backward wave computes w = (E^T D_256)...(E^T D_511) s
// (256 steps). Combine: log(w·u) + logZf + logZb - gold.
// Row-permutation tau(mt,ridx)=32(mt>>1)+8(ridx>>2)+4(mt&1)+(ridx&3) makes
// each lane's C-fragment exactly its next-step B-fragment (kk=mt>>1,
// j=4(mt&1)+r): no LDS, no barriers in the DP loop. Feats: 2 dword/lane ring
// (4-deep lookahead), 2 exps/lane, ds_bpermute redistribution (imm offsets).
// Campaign result: 6 structural variants all regressed with diagnosed causes
// (spill at +32 live VGPRs; co-residency net-negative; M-split barrier cost);
// this is the serial-dependency floor for 1024 chains x 256 steps.
__global__ __launch_bounds__(320, 1)
void crf_split_kernel(const float* __restrict__ feats,
                      const float* __restrict__ trans,
                      const int* __restrict__ tags,
                      float* __restrict__ out) {
  const int tid = threadIdx.x;
  const int wid = tid >> 6;
  const int lane = tid & 63;
  const int bbase = blockIdx.x * 2;

  __shared__ float Uf[2][N_TAG];
  __shared__ float Wb[2][N_TAG];
  __shared__ float LZ[4];
  __shared__ float GOLD[2];

  if (wid == 4) {
    // ---- gold wave: lanes 0-31 batch 0, lanes 32-63 batch 1 ----
    const int half = lane >> 5, tl = lane & 31;
    const int b = bbase + half;
    const int* tg = tags + (size_t)b * T_LEN;
    const float* fg = feats + (size_t)b * T_LEN * N_TAG;
    float gsum = 0.f;
    for (int t = tl; t < T_LEN; t += 32) {
      int tag = tg[t];
      int prev = (t == 0) ? START_TAG : tg[t - 1];
      gsum += trans[(size_t)tag * N_TAG + prev] + fg[(size_t)t * N_TAG + tag];
      if (t == T_LEN - 1) gsum += trans[STOP_TAG * N_TAG + tag];
    }
#pragma unroll
    for (int s = 16; s; s >>= 1) gsum += __shfl_xor(gsum, s);
    if (tl == 0) GOLD[half] = gsum;
    __syncthreads();
    // ---- combine ----
#pragma unroll
    for (int bL = 0; bL < 2; ++bL) {
      float sd = Uf[bL][lane] * Wb[bL][lane] +
                 Uf[bL][lane + 64] * Wb[bL][lane + 64];
#pragma unroll
      for (int s = 32; s; s >>= 1) sd += __shfl_xor(sd, s);
      if (lane == 0)
        out[bbase + bL] = __logf(sd) + LZ[2 * bL] + LZ[2 * bL + 1] - GOLD[bL];
    }
    return;
  }

  // ---- main DP waves: wid = 2*bL + dir (dir 0 fwd, 1 bwd) ----
  const int bL = wid >> 1, dir = wid & 1;
  const int batch = bbase + bL;
  const int n = lane & 15, g = lane >> 4;
  const float* fbase = feats + (size_t)batch * T_LEN * N_TAG;
  const int T0 = dir ? 510 : 0;
  const int TS = dir ? -1 : 1;
  const int ib = 32 * g;  // bpermute base byte address

  // ---- A fragments: tile mt holds E rows tau(mt, ridx); lane supplies
  //      row ridx=n, elements k = 32kk+8g+j. fwd: E[tau][k]; bwd: E[k][tau].
  bf16x8 A[8][4];
#pragma unroll
  for (int mt = 0; mt < 8; ++mt) {
    const int tau = 32 * (mt >> 1) + 8 * (n >> 2) + 4 * (mt & 1) + (n & 3);
#pragma unroll
    for (int kk = 0; kk < 4; ++kk) {
      bf16x8 v;
      if (dir == 0) {
        const float* p = trans + (size_t)tau * N_TAG + 32 * kk + 8 * g;
        f32x4 x = *(const f32x4*)p;
        f32x4 y = *(const f32x4*)(p + 4);
        v[0] = (__bf16)__expf(x[0]); v[1] = (__bf16)__expf(x[1]);
        v[2] = (__bf16)__expf(x[2]); v[3] = (__bf16)__expf(x[3]);
        v[4] = (__bf16)__expf(y[0]); v[5] = (__bf16)__expf(y[1]);
        v[6] = (__bf16)__expf(y[2]); v[7] = (__bf16)__expf(y[3]);
      } else {
#pragma unroll
        for (int j = 0; j < 8; ++j)
          v[j] = (__bf16)__expf(trans[(size_t)(32 * kk + 8 * g + j) * N_TAG + tau]);
      }
      A[mt][kk] = v;
    }
  }

  // ---- B init ----
  bf16x8 Bv[4];
#pragma unroll
  for (int kk = 0; kk < 4; ++kk) {
    bf16x8 z;
#pragma unroll
    for (int j = 0; j < 8; ++j) z[j] = (__bf16)0.0f;
    Bv[kk] = z;
  }
  if (dir == 0) {
    // u_{-1} = one-hot(START=126): tag 126 -> kk=3, g=3, j=6
    if (g == 3) Bv[3][6] = (__bf16)1.0f;
  } else {
    // b0 = ef_511 ⊙ s, s_j = exp(trans[STOP][j]); tag = 32kk+8g+j
    const float* s127 = trans + (size_t)STOP_TAG * N_TAG;
    const float* f511 = fbase + (size_t)(T_LEN - 1) * N_TAG;
#pragma unroll
    for (int kk = 0; kk < 4; ++kk) {
      const int off = 32 * kk + 8 * g;
      f32x4 s0 = *(const f32x4*)(s127 + off);
      f32x4 s1 = *(const f32x4*)(s127 + off + 4);
      f32x4 e0 = *(const f32x4*)(f511 + off);
      f32x4 e1 = *(const f32x4*)(f511 + off + 4);
      bf16x8 v;
      v[0] = (__bf16)__expf(s0[0] + e0[0]); v[1] = (__bf16)__expf(s0[1] + e0[1]);
      v[2] = (__bf16)__expf(s0[2] + e0[2]); v[3] = (__bf16)__expf(s0[3] + e0[3]);
      v[4] = (__bf16)__expf(s1[0] + e1[0]); v[5] = (__bf16)__expf(s1[1] + e1[1]);
      v[6] = (__bf16)__expf(s1[2] + e1[2]); v[7] = (__bf16)__expf(s1[3] + e1[3]);
      Bv[kk] = v;
    }
  }

  // ---- feat ring: slot s holds row t_cur (t==s mod 4); 2 dwords/lane ----
  float Lr[4][2];
#pragma unroll
  for (int s = 0; s < 4; ++s) {
    const float* rp = fbase + (size_t)(T0 + TS * s) * N_TAG;
    Lr[s][0] = rp[lane];
    Lr[s][1] = rp[lane + 64];
  }
  Lr[0][0] = __expf(Lr[0][0]);
  Lr[0][1] = __expf(Lr[0][1]);
  float logZ = 0.0f;

  // EF[mt][r] = ef[tau(mt,4g+r)]; tau = 32a+8g+4bb+r (a=mt>>1, bb=mt&1):
  // a<2 -> reg0 lane tau; a>=2 -> reg1 lane tau-64. Imm-offset bpermutes.
#define BPERM(DST, SLOT)                                                     \
  {                                                                          \
    _Pragma("unroll") for (int a = 0; a < 4; ++a) {                          \
      int sv_ = __float_as_int((a < 2) ? Lr[SLOT][0] : Lr[SLOT][1]);         \
      _Pragma("unroll") for (int bb = 0; bb < 2; ++bb) {                     \
        _Pragma("unroll") for (int r = 0; r < 4; ++r) {                      \
          int w_ = __builtin_amdgcn_ds_bpermute(                             \
              ib + 128 * (a & 1) + 16 * bb + 4 * r, sv_);                    \
          DST[2 * a + bb][r] = __int_as_float(w_);                           \
        }                                                                    \
      }                                                                      \
    }                                                                        \
  }

#define RENORM(ACC)                                                          \
  {                                                                          \
    float mx_ = ACC[0][0];                                                   \
    _Pragma("unroll") for (int mt = 0; mt < 8; ++mt)                         \
        mx_ = fmaxf(mx_, fmaxf(fmaxf(ACC[mt][0], ACC[mt][1]),                \
                               fmaxf(ACC[mt][2], ACC[mt][3])));              \
    mx_ = fmaxf(mx_, __shfl_xor(mx_, 16));                                   \
    mx_ = fmaxf(mx_, __shfl_xor(mx_, 32));                                   \
    int eb_ = __float_as_int(mx_) & 0x7f800000;                              \
    float inv_ = __int_as_float(0x7f000000 - eb_); /* exact 2^-a */          \
    logZ += (float)((eb_ >> 23) - 127) * 0.69314718056f;                     \
    _Pragma("unroll") for (int mt = 0; mt < 8; ++mt) {                       \
      ACC[mt][0] *= inv_; ACC[mt][1] *= inv_;                                \
      ACC[mt][2] *= inv_; ACC[mt][3] *= inv_;                                \
    }                                                                        \
  }

#define ITER(S, SX, KP4, DOREN)                                              \
  {                                                                          \
    f32x4 EF[8];                                                             \
    BPERM(EF, S);                                                            \
    f32x4 acc[8];                                                            \
    _Pragma("unroll") for (int mt = 0; mt < 8; ++mt)                         \
        acc[mt] = (f32x4){0.f, 0.f, 0.f, 0.f};                               \
    _Pragma("unroll") for (int kk = 0; kk < 4; ++kk) {                       \
      _Pragma("unroll") for (int mt = 0; mt < 8; ++mt)                       \
          acc[mt] = __builtin_amdgcn_mfma_f32_16x16x32_bf16(                 \
              A[mt][kk], Bv[kk], acc[mt], 0, 0, 0);                          \
    }                                                                        \
    _Pragma("unroll") for (int mt = 0; mt < 8; ++mt) {                       \
      acc[mt][0] *= EF[mt][0]; acc[mt][1] *= EF[mt][1];                      \
      acc[mt][2] *= EF[mt][2]; acc[mt][3] *= EF[mt][3];                      \
    }                                                                        \
    if (DOREN) RENORM(acc);                                                  \
    _Pragma("unroll") for (int kk = 0; kk < 4; ++kk) {                       \
      bf16x8 nb;                                                             \
      nb[0] = (__bf16)acc[2 * kk][0];     nb[1] = (__bf16)acc[2 * kk][1];    \
      nb[2] = (__bf16)acc[2 * kk][2];     nb[3] = (__bf16)acc[2 * kk][3];    \
      nb[4] = (__bf16)acc[2 * kk + 1][0]; nb[5] = (__bf16)acc[2 * kk + 1][1];\
      nb[6] = (__bf16)acc[2 * kk + 1][2]; nb[7] = (__bf16)acc[2 * kk + 1][3];\
      Bv[kk] = nb;                                                           \
    }                                                                        \
    Lr[SX][0] = __expf(Lr[SX][0]); /* next step's ef (landed 3 iters ago) */ \
    Lr[SX][1] = __expf(Lr[SX][1]);                                           \
    {                                                                        \
      const float* rp_ = fbase + (size_t)(T0 + TS * (KP4)) * N_TAG;          \
      Lr[S][0] = rp_[lane]; /* refill slot: 4-iter lookahead */              \
      Lr[S][1] = rp_[lane + 64];                                             \
    }                                                                        \
  }

  // ---- 255 full steps + tail: 256 MFMA steps total ----
  for (int kb = 0; kb < 63; ++kb) {
    const int k0 = kb * 4;
    ITER(0, 1, k0 + 4, false);
    ITER(1, 2, k0 + 5, false);
    ITER(2, 3, k0 + 6, false);
    ITER(3, 0, k0 + 7, true);
  }
  ITER(0, 1, 256, false);  // k=252
  ITER(1, 2, 257, false);  // k=253
  ITER(2, 3, 258, false);  // k=254

  // ---- tail (k=255): fwd multiplies ef_255; bwd keeps raw E^T·b ----
  f32x4 upF[8];
  {
    f32x4 EF[8];
    BPERM(EF, 3);
    f32x4 acc[8];
#pragma unroll
    for (int mt = 0; mt < 8; ++mt) acc[mt] = (f32x4){0.f, 0.f, 0.f, 0.f};
#pragma unroll
    for (int kk = 0; kk < 4; ++kk) {
#pragma unroll
      for (int mt = 0; mt < 8; ++mt)
        acc[mt] = __builtin_amdgcn_mfma_f32_16x16x32_bf16(A[mt][kk], Bv[kk],
                                                          acc[mt], 0, 0, 0);
    }
    if (dir == 0) {
#pragma unroll
      for (int mt = 0; mt < 8; ++mt) {
        acc[mt][0] *= EF[mt][0]; acc[mt][1] *= EF[mt][1];
        acc[mt][2] *= EF[mt][2]; acc[mt][3] *= EF[mt][3];
      }
    }
    RENORM(acc);  // final normalization so the dot can't overflow f32
#pragma unroll
    for (int mt = 0; mt < 8; ++mt) upF[mt] = acc[mt];
  }

  // ---- publish final vectors (plain tag order) ----
  float* dst = (dir == 0) ? Uf[bL] : Wb[bL];
  if (n == 0) {
#pragma unroll
    for (int mt = 0; mt < 8; ++mt) {
      const int base = 32 * (mt >> 1) + 8 * g + 4 * (mt & 1);
#pragma unroll
      for (int r = 0; r < 4; ++r) dst[base + r] = upF[mt][r];
    }
  }
  if (lane == 0) LZ[wid] = logZ;
  __syncthreads();
#undef ITER
#undef RENORM
#undef BPERM
}

extern "C" void kernel_launch(void* const* d_in, const int* in_sizes, int n_in,
                              void* d_out, int out_size, void* d_ws, size_t ws_size,
                              hipStream_t stream) {
  const float* feats = (const float*)d_in[0];
  const float* trans = (const float*)d_in[1];
  const int* tags = (const int*)d_in[2];
  float* out = (float*)d_out;
  int B = in_sizes[0] / (T_LEN * N_TAG);  // 512
  crf_split_kernel<<<B / 2, 320, 0, stream>>>(feats, trans, tags, out);
}

// Round 22
// 134.272 us; speedup vs baseline: 4.2155x; 1.1082x over previous
//
#include <hip/hip_runtime.h>
#include <hip/hip_bf16.h>

#define N_TAG 128
#define T_LEN 512
#define START_TAG 126
#define STOP_TAG 127

typedef __attribute__((ext_vector_type(8))) __bf16 bf16x8;
typedef __attribute__((ext_vector_type(4))) float f32x4;

// Round 22 = r10 (149us, absmax 0) with the EF gather halved: ring pair
// (ef[lane], ef[lane+64]) packed to one dword via v_cvt_pk_bf16_f32 at the
// existing exp point; 16 bpermutes (was 32) fetch quads a and a+2 together
// (tau(a+2) = tau(a)+64 = same lane addr, other half of the pair). Unpack is
// 2 private VALU ops. Rationale: DS pipe is per-CU, shared by 4 DP waves
// (r17: +250cy/step DS contention per extra 32-bperm wave); VALU is per-SIMD.
__global__ __launch_bounds__(320, 1)
void crf_split_kernel(const float* __restrict__ feats,
                      const float* __restrict__ trans,
                      const int* __restrict__ tags,
                      float* __restrict__ out) {
  const int tid = threadIdx.x;
  const int wid = tid >> 6;
  const int lane = tid & 63;
  const int bbase = blockIdx.x * 2;

  __shared__ float Uf[2][N_TAG];
  __shared__ float Wb[2][N_TAG];
  __shared__ float LZ[4];
  __shared__ float GOLD[2];

  if (wid == 4) {
    // ---- gold wave: lanes 0-31 batch 0, lanes 32-63 batch 1 ----
    const int half = lane >> 5, tl = lane & 31;
    const int b = bbase + half;
    const int* tg = tags + (size_t)b * T_LEN;
    const float* fg = feats + (size_t)b * T_LEN * N_TAG;
    float gsum = 0.f;
    for (int t = tl; t < T_LEN; t += 32) {
      int tag = tg[t];
      int prev = (t == 0) ? START_TAG : tg[t - 1];
      gsum += trans[(size_t)tag * N_TAG + prev] + fg[(size_t)t * N_TAG + tag];
      if (t == T_LEN - 1) gsum += trans[STOP_TAG * N_TAG + tag];
    }
#pragma unroll
    for (int s = 16; s; s >>= 1) gsum += __shfl_xor(gsum, s);
    if (tl == 0) GOLD[half] = gsum;
    __syncthreads();
    // ---- combine ----
#pragma unroll
    for (int bL = 0; bL < 2; ++bL) {
      float sd = Uf[bL][lane] * Wb[bL][lane] +
                 Uf[bL][lane + 64] * Wb[bL][lane + 64];
#pragma unroll
      for (int s = 32; s; s >>= 1) sd += __shfl_xor(sd, s);
      if (lane == 0)
        out[bbase + bL] = __logf(sd) + LZ[2 * bL] + LZ[2 * bL + 1] - GOLD[bL];
    }
    return;
  }

  // ---- main DP waves: wid = 2*bL + dir (dir 0 fwd, 1 bwd) ----
  const int bL = wid >> 1, dir = wid & 1;
  const int batch = bbase + bL;
  const int n = lane & 15, g = lane >> 4;
  const float* fbase = feats + (size_t)batch * T_LEN * N_TAG;
  const int T0 = dir ? 510 : 0;
  const int TS = dir ? -1 : 1;
  const int ib = 32 * g;  // bpermute base byte address

  // ---- A fragments: tile mt holds E rows tau(mt, ridx); lane supplies
  //      row ridx=n, elements k = 32kk+8g+j. fwd: E[tau][k]; bwd: E[k][tau].
  bf16x8 A[8][4];
#pragma unroll
  for (int mt = 0; mt < 8; ++mt) {
    const int tau = 32 * (mt >> 1) + 8 * (n >> 2) + 4 * (mt & 1) + (n & 3);
#pragma unroll
    for (int kk = 0; kk < 4; ++kk) {
      bf16x8 v;
      if (dir == 0) {
        const float* p = trans + (size_t)tau * N_TAG + 32 * kk + 8 * g;
        f32x4 x = *(const f32x4*)p;
        f32x4 y = *(const f32x4*)(p + 4);
        v[0] = (__bf16)__expf(x[0]); v[1] = (__bf16)__expf(x[1]);
        v[2] = (__bf16)__expf(x[2]); v[3] = (__bf16)__expf(x[3]);
        v[4] = (__bf16)__expf(y[0]); v[5] = (__bf16)__expf(y[1]);
        v[6] = (__bf16)__expf(y[2]); v[7] = (__bf16)__expf(y[3]);
      } else {
#pragma unroll
        for (int j = 0; j < 8; ++j)
          v[j] = (__bf16)__expf(trans[(size_t)(32 * kk + 8 * g + j) * N_TAG + tau]);
      }
      A[mt][kk] = v;
    }
  }

  // ---- B init ----
  bf16x8 Bv[4];
#pragma unroll
  for (int kk = 0; kk < 4; ++kk) {
    bf16x8 z;
#pragma unroll
    for (int j = 0; j < 8; ++j) z[j] = (__bf16)0.0f;
    Bv[kk] = z;
  }
  if (dir == 0) {
    // u_{-1} = one-hot(START=126): tag 126 -> kk=3, g=3, j=6
    if (g == 3) Bv[3][6] = (__bf16)1.0f;
  } else {
    // b0 = ef_511 ⊙ s, s_j = exp(trans[STOP][j]); tag = 32kk+8g+j
    const float* s127 = trans + (size_t)STOP_TAG * N_TAG;
    const float* f511 = fbase + (size_t)(T_LEN - 1) * N_TAG;
#pragma unroll
    for (int kk = 0; kk < 4; ++kk) {
      const int off = 32 * kk + 8 * g;
      f32x4 s0 = *(const f32x4*)(s127 + off);
      f32x4 s1 = *(const f32x4*)(s127 + off + 4);
      f32x4 e0 = *(const f32x4*)(f511 + off);
      f32x4 e1 = *(const f32x4*)(f511 + off + 4);
      bf16x8 v;
      v[0] = (__bf16)__expf(s0[0] + e0[0]); v[1] = (__bf16)__expf(s0[1] + e0[1]);
      v[2] = (__bf16)__expf(s0[2] + e0[2]); v[3] = (__bf16)__expf(s0[3] + e0[3]);
      v[4] = (__bf16)__expf(s1[0] + e1[0]); v[5] = (__bf16)__expf(s1[1] + e1[1]);
      v[6] = (__bf16)__expf(s1[2] + e1[2]); v[7] = (__bf16)__expf(s1[3] + e1[3]);
      Bv[kk] = v;
    }
  }

  // ---- feat ring: slot s holds raw rows (t==s mod 4), 2 dwords/lane.
  //      Pk[s] = packed bf16 pair (exp(raw0) | exp(raw1)<<16), built at the
  //      old exp point (1 iter before use). ----
  float Lr[4][2];
  int Pk[4];
#pragma unroll
  for (int s = 0; s < 4; ++s) {
    const float* rp = fbase + (size_t)(T0 + TS * s) * N_TAG;
    Lr[s][0] = rp[lane];
    Lr[s][1] = rp[lane + 64];
  }
  {
    float e0 = __expf(Lr[0][0]);
    float e1 = __expf(Lr[0][1]);
    asm("v_cvt_pk_bf16_f32 %0, %1, %2" : "=v"(Pk[0]) : "v"(e0), "v"(e1));
  }
  float logZ = 0.0f;

  // EF[2a+bb][r] = ef[tau(a,bb,r)], tau = 32a+8g+4bb+r. Pair fetch: one
  // bpermute at lane (32*a2+8g+4bb+r) of Pk returns lo=ef[tau(a2)] and
  // hi=ef[tau(a2)+64]=ef[tau(a2+2)] -> 16 bpermutes cover all 32 values.
#define BPERM(DST, SLOT)                                                     \
  {                                                                          \
    _Pragma("unroll") for (int a2 = 0; a2 < 2; ++a2) {                       \
      _Pragma("unroll") for (int bb = 0; bb < 2; ++bb) {                     \
        _Pragma("unroll") for (int r = 0; r < 4; ++r) {                      \
          int w_ = __builtin_amdgcn_ds_bpermute(                             \
              ib + 128 * a2 + 16 * bb + 4 * r, Pk[SLOT]);                    \
          DST[2 * a2 + bb][r] = __int_as_float(w_ << 16);                    \
          DST[4 + 2 * a2 + bb][r] =                                          \
              __int_as_float((int)(w_ & 0xffff0000u));                       \
        }                                                                    \
      }                                                                      \
    }                                                                        \
  }

#define RENORM(ACC)                                                          \
  {                                                                          \
    float mx_ = ACC[0][0];                                                   \
    _Pragma("unroll") for (int mt = 0; mt < 8; ++mt)                         \
        mx_ = fmaxf(mx_, fmaxf(fmaxf(ACC[mt][0], ACC[mt][1]),                \
                               fmaxf(ACC[mt][2], ACC[mt][3])));              \
    mx_ = fmaxf(mx_, __shfl_xor(mx_, 16));                                   \
    mx_ = fmaxf(mx_, __shfl_xor(mx_, 32));                                   \
    int eb_ = __float_as_int(mx_) & 0x7f800000;                              \
    float inv_ = __int_as_float(0x7f000000 - eb_); /* exact 2^-a */          \
    logZ += (float)((eb_ >> 23) - 127) * 0.69314718056f;                     \
    _Pragma("unroll") for (int mt = 0; mt < 8; ++mt) {                       \
      ACC[mt][0] *= inv_; ACC[mt][1] *= inv_;                                \
      ACC[mt][2] *= inv_; ACC[mt][3] *= inv_;                                \
    }                                                                        \
  }

#define ITER(S, SX, KP4, DOREN)                                              \
  {                                                                          \
    f32x4 EF[8];                                                             \
    BPERM(EF, S);                                                            \
    f32x4 acc[8];                                                            \
    _Pragma("unroll") for (int mt = 0; mt < 8; ++mt)                         \
        acc[mt] = (f32x4){0.f, 0.f, 0.f, 0.f};                               \
    _Pragma("unroll") for (int kk = 0; kk < 4; ++kk) {                       \
      _Pragma("unroll") for (int mt = 0; mt < 8; ++mt)                       \
          acc[mt] = __builtin_amdgcn_mfma_f32_16x16x32_bf16(                 \
              A[mt][kk], Bv[kk], acc[mt], 0, 0, 0);                          \
    }                                                                        \
    _Pragma("unroll") for (int mt = 0; mt < 8; ++mt) {                       \
      acc[mt][0] *= EF[mt][0]; acc[mt][1] *= EF[mt][1];                      \
      acc[mt][2] *= EF[mt][2]; acc[mt][3] *= EF[mt][3];                      \
    }                                                                        \
    if (DOREN) RENORM(acc);                                                  \
    _Pragma("unroll") for (int kk = 0; kk < 4; ++kk) {                       \
      bf16x8 nb;                                                             \
      nb[0] = (__bf16)acc[2 * kk][0];     nb[1] = (__bf16)acc[2 * kk][1];    \
      nb[2] = (__bf16)acc[2 * kk][2];     nb[3] = (__bf16)acc[2 * kk][3];    \
      nb[4] = (__bf16)acc[2 * kk + 1][0]; nb[5] = (__bf16)acc[2 * kk + 1][1];\
      nb[6] = (__bf16)acc[2 * kk + 1][2]; nb[7] = (__bf16)acc[2 * kk + 1][3];\
      Bv[kk] = nb;                                                           \
    }                                                                        \
    {                                                                        \
      float e0_ = __expf(Lr[SX][0]); /* next step's ef (landed 3 iters ago)*/\
      float e1_ = __expf(Lr[SX][1]);                                         \
      asm("v_cvt_pk_bf16_f32 %0, %1, %2"                                     \
          : "=v"(Pk[SX]) : "v"(e0_), "v"(e1_));                              \
    }                                                                        \
    {                                                                        \
      const float* rp_ = fbase + (size_t)(T0 + TS * (KP4)) * N_TAG;          \
      Lr[S][0] = rp_[lane]; /* refill slot: 4-iter lookahead */              \
      Lr[S][1] = rp_[lane + 64];                                             \
    }                                                                        \
  }

  // ---- 255 full steps + tail: 256 MFMA steps total ----
  for (int kb = 0; kb < 63; ++kb) {
    const int k0 = kb * 4;
    ITER(0, 1, k0 + 4, false);
    ITER(1, 2, k0 + 5, false);
    ITER(2, 3, k0 + 6, false);
    ITER(3, 0, k0 + 7, true);
  }
  ITER(0, 1, 256, false);  // k=252
  ITER(1, 2, 257, false);  // k=253
  ITER(2, 3, 258, false);  // k=254

  // ---- tail (k=255): fwd multiplies ef_255; bwd keeps raw E^T·b ----
  f32x4 upF[8];
  {
    f32x4 EF[8];
    BPERM(EF, 3);
    f32x4 acc[8];
#pragma unroll
    for (int mt = 0; mt < 8; ++mt) acc[mt] = (f32x4){0.f, 0.f, 0.f, 0.f};
#pragma unroll
    for (int kk = 0; kk < 4; ++kk) {
#pragma unroll
      for (int mt = 0; mt < 8; ++mt)
        acc[mt] = __builtin_amdgcn_mfma_f32_16x16x32_bf16(A[mt][kk], Bv[kk],
                                                          acc[mt], 0, 0, 0);
    }
    if (dir == 0) {
#pragma unroll
      for (int mt = 0; mt < 8; ++mt) {
        acc[mt][0] *= EF[mt][0]; acc[mt][1] *= EF[mt][1];
        acc[mt][2] *= EF[mt][2]; acc[mt][3] *= EF[mt][3];
      }
    }
    RENORM(acc);  // final normalization so the dot can't overflow f32
#pragma unroll
    for (int mt = 0; mt < 8; ++mt) upF[mt] = acc[mt];
  }

  // ---- publish final vectors (plain tag order) ----
  float* dst = (dir == 0) ? Uf[bL] : Wb[bL];
  if (n == 0) {
#pragma unroll
    for (int mt = 0; mt < 8; ++mt) {
      const int base = 32 * (mt >> 1) + 8 * g + 4 * (mt & 1);
#pragma unroll
      for (int r = 0; r < 4; ++r) dst[base + r] = upF[mt][r];
    }
  }
  if (lane == 0) LZ[wid] = logZ;
  __syncthreads();
#undef ITER
#undef RENORM
#undef BPERM
}

extern "C" void kernel_launch(void* const* d_in, const int* in_sizes, int n_in,
                              void* d_out, int out_size, void* d_ws, size_t ws_size,
                              hipStream_t stream) {
  const float* feats = (const float*)d_in[0];
  const float* trans = (const float*)d_in[1];
  const int* tags = (const int*)d_in[2];
  float* out = (float*)d_out;
  int B = in_sizes[0] / (T_LEN * N_TAG);  // 512
  crf_split_kernel<<<B / 2, 320, 0, stream>>>(feats, trans, tags, out);
}